// Round 13
// baseline (152.619 us; speedup 1.0000x reference)
//
#include <hip/hip_runtime.h>
#include <hip/hip_bf16.h>

// CausalAttentionPixelBlock: 24 independent causal attns (3 stacks x 8 heads),
// seq=2048, head dim ck=8, fp32 in/out, channels-first [c][pos].
// R13 = AMPLIFIED MEASUREMENT ROUND on the best kernel (r10, 91.2us):
// both kernels repeat their work 8x in-kernel so they surface in rocprof's
// top-5 with counters (fills are 41-44us; our kernels were invisible below).
// attn_main's repeat is output-invariant: acc AND rowsum scale 8x; out =
// acc/rowsum cancels. prepass rewrites identical values (mem clobber between
// reps). One change rides along: exp2f -> __builtin_amdgcn_exp2f (raw
// v_exp_f32, no libm range-guard VALU).
constexpr int NPROB  = 24;
constexpr int SEQ    = 2048;
constexpr int CK     = 8;
constexpr int NSTRIP = SEQ / 16;   // 128 strips of 16 query rows per prob
constexpr int REP    = 8;          // measurement amplification

typedef __attribute__((ext_vector_type(8))) short bf16x8;  // MFMA A/B frag (8 bf16)
typedef __attribute__((ext_vector_type(4))) float f32x4;   // MFMA C/D frag

#if __has_builtin(__builtin_amdgcn_exp2f)
#define EXP2F(x) __builtin_amdgcn_exp2f(x)
#else
#define EXP2F(x) exp2f(x)
#endif

// ck^-0.5 * log2(e): exp(x) -> exp2(x') with scale folded into Q
__device__ constexpr float QSCALE = 0.35355339059327373f * 1.4426950408889634f;

__device__ inline unsigned packbf(float a, float b) {
    float2 t{a, b};
    __hip_bfloat162 h = __float22bfloat162_rn(t);
    unsigned r; __builtin_memcpy(&r, &h, 4); return r;
}

// ---------------- prepass: fp32 -> bf16 fragments in ws ----------------
// Qt: [prob][j][8] bf16 (Q transposed, pre-scaled)                     786 KB
// Kt: [prob][j][8] bf16 (K transposed)                                 786 KB
// V16:[prob][chunk][64] uint4, chunk = 32 keys. Entry (chunk p, l=g*16+row):
//     V[row][32p + {4g..4g+3, 16+4g..16+4g+3}] (sigma key order). Row 8 = 1.0
//     (free rowsum), rows 9-15 = 0.                                    1.57 MB
constexpr int TA = NPROB * SEQ * 4;        // Qt+Kt: (prob, j, cpair)   196608
constexpr int TB = NPROB * CK * (SEQ / 8); // V16 rows 0-7               49152
constexpr int TC = NPROB * 8  * (SEQ / 8); // V16 rows 8-15 fill         49152

__global__ __launch_bounds__(256) void prepass(
    const float* __restrict__ K, const float* __restrict__ Q,
    const float* __restrict__ V,
    uint4* __restrict__ Qt4, uint4* __restrict__ Kt4, uint4* __restrict__ V164)
{
    const int t = blockIdx.x * 256 + threadIdx.x;
    for (int rep = 0; rep < REP; ++rep) {
        if (t < TA) {
            const int cp   = t & 3;            // channel pair 0..3
            const int j    = (t >> 2) & (SEQ - 1);
            const int prob = t >> 13;
            const float* qs = Q + prob * CK * SEQ + (cp << 1) * SEQ + j;
            const float* ks = K + prob * CK * SEQ + (cp << 1) * SEQ + j;
            ((unsigned*)Qt4)[t] = packbf(qs[0] * QSCALE, qs[SEQ] * QSCALE);
            ((unsigned*)Kt4)[t] = packbf(ks[0], ks[SEQ]);
        } else if (t < TA + TB) {
            const int idx  = t - TA;
            const int prob = idx >> 11;
            const int rem  = idx & 2047;
            const int c    = rem >> 8;             // V row (channel) 0..7
            const int u    = rem & 255;
            const int c32  = u >> 2;               // 32-key chunk 0..63
            const int g    = u & 3;                // k-group within chunk
            const float* vs = V + prob * CK * SEQ + c * SEQ + c32 * 32;
            const float4 a = *reinterpret_cast<const float4*>(vs + 4 * g);
            const float4 b = *reinterpret_cast<const float4*>(vs + 16 + 4 * g);
            uint4 vo;
            vo.x = packbf(a.x, a.y); vo.y = packbf(a.z, a.w);
            vo.z = packbf(b.x, b.y); vo.w = packbf(b.z, b.w);
            V164[prob * 4096 + c32 * 64 + g * 16 + c] = vo;   // [prob][chunk][g*16+row]
        } else {
            const int idx  = t - TA - TB;
            const int prob = idx >> 11;
            const int rem  = idx & 2047;
            const int r    = rem >> 8;             // 0..7 -> row 8+r
            const int u    = rem & 255;
            const int c32  = u >> 2;
            const int g    = u & 3;
            const unsigned w = (r == 0) ? 0x3F803F80u : 0u;  // row 8 = ones (rowsum)
            V164[prob * 4096 + c32 * 64 + g * 16 + (8 + r)] = uint4{w, w, w, w};
        }
        asm volatile("" ::: "memory");   // keep each rep's loads+stores live
    }
}

// ---------------- main: one 4-wave block per 16-row strip (r10 structure) ----
// QK transposed: d = mfma16x16x32(A=K, B=Q) -> lane(g,li) reg r = P[j'=4g+r(+16)][i'=li].
// exp2 in place, pack to bf16: pa = {d0r01, d0r23, d1r01, d1r23} is EXACTLY the
// PV A-frag under key-order sigma(8g+e) = 4g+e | 16+4g+(e-4); V staged in sigma
// order, so PV = mfma(pa, V) with no cross-lane ops. V row 8 = ones gives the
// softmax denominator in acc col 8.
__global__ __launch_bounds__(256) void attn_main(
    const uint4* __restrict__ Qt4, const uint4* __restrict__ Kt4,
    const uint4* __restrict__ V164, float* __restrict__ OUT)
{
    const int bid   = blockIdx.x;
    const int prob  = bid % NPROB;
    const int strip = (NSTRIP - 1) - (bid / NPROB);  // longest first
    const int i0    = strip * 16;
    const int t  = threadIdx.x;
    const int w  = t >> 6;                  // wave 0..3
    const int l  = t & 63;                  // lane
    const int li = l & 15, g = l >> 4;

    const uint4* Ktp = Kt4 + prob * SEQ;
    const uint4* Vp  = V164 + prob * 4096;  // [64 chunks][64] uint4

    union { bf16x8 v; uint4 u; } qf;
    qf.u = (g == 0) ? Qt4[prob * SEQ + i0 + li] : uint4{0, 0, 0, 0};

    f32x4 acc = {0.f, 0.f, 0.f, 0.f};
    const f32x4 zc = {0.f, 0.f, 0.f, 0.f};
    const int mconst = li - 4 * g;          // diag tile: keep reg r iff r <= mconst

    const int NU = i0 >> 5;                 // fully-unmasked 32-j iterations

    // REP x the whole accumulation: out = acc/rowsum is invariant to the x8.
    for (int rep = 0; rep < REP; ++rep) {
#pragma unroll 2
        for (int p = w; p < NU; p += 4) {
            const int j0 = p * 32;
            union { bf16x8 v; uint4 u; } k0, k1, vf;
            k0.u = Ktp[j0 + li];                // keys j0..j0+15 (broadcast x4)
            k1.u = Ktp[j0 + 16 + li];           // keys j0+16..j0+31
            vf.u = Vp[(p << 6) + l];            // sigma-interleaved V, coalesced
            f32x4 d0 = __builtin_amdgcn_mfma_f32_16x16x32_bf16(k0.v, qf.v, zc, 0, 0, 0);
            f32x4 d1 = __builtin_amdgcn_mfma_f32_16x16x32_bf16(k1.v, qf.v, zc, 0, 0, 0);
#pragma unroll
            for (int r = 0; r < 4; ++r) { d0[r] = EXP2F(d0[r]); d1[r] = EXP2F(d1[r]); }
            union { bf16x8 v; unsigned u[4]; } pa;
            pa.u[0] = packbf(d0[0], d0[1]);
            pa.u[1] = packbf(d0[2], d0[3]);
            pa.u[2] = packbf(d1[0], d1[1]);
            pa.u[3] = packbf(d1[2], d1[3]);
            acc = __builtin_amdgcn_mfma_f32_16x16x32_bf16(pa.v, vf.v, acc, 0, 0, 0);
        }

        // remainder (iteration index NU): diagonal region, owned by wave NU&3
        if ((NU & 3) == w) {
            const int j0 = NU * 32;
            union { bf16x8 v; uint4 u; } k0, k1, vf;
            union { bf16x8 v; unsigned u[4]; } pa;
            vf.u = Vp[(NU << 6) + l];
            if (i0 & 16) {
                k0.u = Ktp[j0 + li];
                k1.u = Ktp[j0 + 16 + li];
                f32x4 d0 = __builtin_amdgcn_mfma_f32_16x16x32_bf16(k0.v, qf.v, zc, 0, 0, 0);
                f32x4 d1 = __builtin_amdgcn_mfma_f32_16x16x32_bf16(k1.v, qf.v, zc, 0, 0, 0);
#pragma unroll
                for (int r = 0; r < 4; ++r) {
                    d0[r] = EXP2F(d0[r]);
                    d1[r] = (r <= mconst) ? EXP2F(d1[r]) : 0.f;
                }
                pa.u[0] = packbf(d0[0], d0[1]);
                pa.u[1] = packbf(d0[2], d0[3]);
                pa.u[2] = packbf(d1[0], d1[1]);
                pa.u[3] = packbf(d1[2], d1[3]);
            } else {
                k0.u = Ktp[j0 + li];
                f32x4 d0 = __builtin_amdgcn_mfma_f32_16x16x32_bf16(k0.v, qf.v, zc, 0, 0, 0);
#pragma unroll
                for (int r = 0; r < 4; ++r)
                    d0[r] = (r <= mconst) ? EXP2F(d0[r]) : 0.f;
                pa.u[0] = packbf(d0[0], d0[1]);
                pa.u[1] = packbf(d0[2], d0[3]);
                pa.u[2] = 0u;
                pa.u[3] = 0u;
            }
            acc = __builtin_amdgcn_mfma_f32_16x16x32_bf16(pa.v, vf.v, acc, 0, 0, 0);
        }
    }

    // merge 4 waves' additive partials through LDS (b128, 2-way conflict = free)
    __shared__ f32x4 lds[4][64];
    lds[w][l] = acc;
    __syncthreads();
    if (w != 0) return;
#pragma unroll
    for (int ww = 1; ww < 4; ++ww) {
        const f32x4 o = lds[ww][l];
#pragma unroll
        for (int r = 0; r < 4; ++r) acc[r] += o[r];
    }

    // acc = D[row=4g+r][col=li]; col 8 = rowsum*REP (ones row of V) -> ratio
    // out = acc/rowsum is REP-invariant.
    const int idxR = ((g << 4) + 8) << 2;
    float inv[4];
#pragma unroll
    for (int r = 0; r < 4; ++r) {
        const float rs = __int_as_float(
            __builtin_amdgcn_ds_bpermute(idxR, __float_as_int(acc[r])));
        inv[r] = 1.0f / rs;
    }
    if (li < CK) {
#pragma unroll
        for (int r = 0; r < 4; ++r)
            OUT[(prob * CK + li) * SEQ + i0 + 4 * g + r] = acc[r] * inv[r];
    }
}

extern "C" void kernel_launch(void* const* d_in, const int* in_sizes, int n_in,
                              void* d_out, int out_size, void* d_ws, size_t ws_size,
                              hipStream_t stream) {
    // setup_inputs order: keys, queries, values, attn_mask (=tril, folded), num_heads (=8)
    const float* K = (const float*)d_in[0];
    const float* Q = (const float*)d_in[1];
    const float* V = (const float*)d_in[2];
    float* OUT = (float*)d_out;

    // ws layout (bytes): Qt[0, 786432) Kt[786432, 1572864) V16[1572864, 3145728)
    uint4* Qt4  = (uint4*)d_ws;
    uint4* Kt4  = (uint4*)((char*)d_ws + 786432);
    uint4* V164 = (uint4*)((char*)d_ws + 1572864);

    prepass<<<dim3((TA + TB + TC) / 256), dim3(256), 0, stream>>>(K, Q, V, Qt4, Kt4, V164);
    attn_main<<<dim3(NPROB * NSTRIP), dim3(256), 0, stream>>>(Qt4, Kt4, V164, OUT);
}